// Round 1
// baseline (359.323 us; speedup 1.0000x reference)
//
#include <hip/hip_runtime.h>

// Problem geometry (fixed by setup_inputs): [16, 1, 352, 1216] fp32.
#define BATCH 16
#define HH    352
#define WW    1216
#define IMG   (HH * WW)
#define QPR   (WW / 4)        // 304 quads per row
#define QPI   (QPR * HH)      // 107008 quads per image
#define BLOCK 256
#define GRIDX (QPI / BLOCK)   // 418 blocks per image, exact

__device__ __forceinline__ void cmpex(float& a, float& b) {
    float t = fminf(a, b);
    b = fmaxf(a, b);
    a = t;
}

__device__ __forceinline__ float med3f(float a, float b, float c) {
#if defined(__has_builtin) && __has_builtin(__builtin_amdgcn_fmed3f)
    return __builtin_amdgcn_fmed3f(a, b, c);
#else
    return fmaxf(fminf(fmaxf(a, b), c), fminf(a, b));
#endif
}

// Load 6 contiguous values (w0-1 .. w0+4) of row h, zero-padded at all edges.
__device__ __forceinline__ void load6(const float* img, int h, int w0, float o[6]) {
    if (h < 0 || h >= HH) {
        o[0] = o[1] = o[2] = o[3] = o[4] = o[5] = 0.0f;
        return;
    }
    const float* r = img + h * WW + w0;
    float4 v = *reinterpret_cast<const float4*>(r);
    o[1] = v.x; o[2] = v.y; o[3] = v.z; o[4] = v.w;
    o[0] = (w0 > 0)       ? r[-1] : 0.0f;
    o[5] = (w0 + 4 < WW)  ? r[4]  : 0.0f;
}

// contrast[i] = center - median3x3 for 4 consecutive pixels (h, w0..w0+3).
// Exact median-of-9 via per-column sort3 + med3(max3(lo), med3(mid), min3(hi)).
__device__ __forceinline__ void quad_contrast(const float* img, int h, int w0, float c[4]) {
    float r0[6], r1[6], r2[6];
    load6(img, h - 1, w0, r0);
    load6(img, h,     w0, r1);
    load6(img, h + 1, w0, r2);
    float lo[6], mid[6], hi[6];
#pragma unroll
    for (int j = 0; j < 6; ++j) {
        float a = r0[j], b = r1[j], d = r2[j];
        cmpex(a, b); cmpex(b, d); cmpex(a, b);   // a <= b <= d
        lo[j] = a; mid[j] = b; hi[j] = d;
    }
#pragma unroll
    for (int i = 0; i < 4; ++i) {
        float mx = fmaxf(fmaxf(lo[i], lo[i + 1]), lo[i + 2]);   // v_max3
        float md = med3f(mid[i], mid[i + 1], mid[i + 2]);       // v_med3
        float mn = fminf(fminf(hi[i], hi[i + 1]), hi[i + 2]);   // v_min3
        c[i] = r1[i + 1] - med3f(mx, md, mn);
    }
}

__device__ __forceinline__ float waveRed(float v) {
#pragma unroll
    for (int o = 32; o > 0; o >>= 1) v += __shfl_down(v, o, 64);
    return v;
}

// Pass 1: per-image sums of mask, mask*|pred_contrast|, mask*|target_contrast|.
__global__ __launch_bounds__(BLOCK) void pass1(const float* __restrict__ pred,
                                               const float* __restrict__ tgt,
                                               const float* __restrict__ mask,
                                               float* __restrict__ sums) {
    const int b = blockIdx.y;
    const int quad = blockIdx.x * BLOCK + threadIdx.x;
    const int h  = quad / QPR;
    const int w0 = (quad - h * QPR) * 4;

    const float* pimg = pred + b * IMG;
    const float* timg = tgt  + b * IMG;

    float4 m4 = *reinterpret_cast<const float4*>(mask + b * IMG + h * WW + w0);
    float mv[4] = {m4.x, m4.y, m4.z, m4.w};

    float pc[4], tc[4];
    quad_contrast(pimg, h, w0, pc);
    quad_contrast(timg, h, w0, tc);

    float s_m = 0.f, s_p = 0.f, s_t = 0.f;
#pragma unroll
    for (int i = 0; i < 4; ++i) {
        s_m += mv[i];
        s_p += mv[i] * fabsf(pc[i]);
        s_t += mv[i] * fabsf(tc[i]);
    }

    s_m = waveRed(s_m); s_p = waveRed(s_p); s_t = waveRed(s_t);

    __shared__ float red[3][4];
    const int lane = threadIdx.x & 63, wid = threadIdx.x >> 6;
    if (lane == 0) { red[0][wid] = s_m; red[1][wid] = s_p; red[2][wid] = s_t; }
    __syncthreads();
    if (threadIdx.x == 0) {
        atomicAdd(&sums[b * 3 + 0], red[0][0] + red[0][1] + red[0][2] + red[0][3]);
        atomicAdd(&sums[b * 3 + 1], red[1][0] + red[1][1] + red[1][2] + red[1][3]);
        atomicAdd(&sums[b * 3 + 2], red[2][0] + red[2][1] + red[2][2] + red[2][3]);
    }
}

// Pass 2: sum over all pixels of |pc/mean_pred - tc/mean_target|.
__global__ __launch_bounds__(BLOCK) void pass2(const float* __restrict__ pred,
                                               const float* __restrict__ tgt,
                                               const float* __restrict__ mask,
                                               const float* __restrict__ sums,
                                               float* __restrict__ acc) {
    const int b = blockIdx.y;
    const float denom  = sums[b * 3 + 0];
    const float inv_mp = denom / sums[b * 3 + 1];  // 1 / mean_pred
    const float inv_mt = denom / sums[b * 3 + 2];  // 1 / mean_target

    const int quad = blockIdx.x * BLOCK + threadIdx.x;
    const int h  = quad / QPR;
    const int w0 = (quad - h * QPR) * 4;

    const float* pimg = pred + b * IMG;
    const float* timg = tgt  + b * IMG;

    float pc[4], tc[4];
    quad_contrast(pimg, h, w0, pc);
    quad_contrast(timg, h, w0, tc);

    float s = 0.f;
#pragma unroll
    for (int i = 0; i < 4; ++i)
        s += fabsf(pc[i] * inv_mp - tc[i] * inv_mt);

    s = waveRed(s);

    __shared__ float red[4];
    const int lane = threadIdx.x & 63, wid = threadIdx.x >> 6;
    if (lane == 0) red[wid] = s;
    __syncthreads();
    if (threadIdx.x == 0)
        atomicAdd(acc, red[0] + red[1] + red[2] + red[3]);

    (void)mask;
}

__global__ void finalize(const float* __restrict__ sums,
                         const float* __restrict__ acc,
                         float* __restrict__ out) {
    float tm = 0.f;
    for (int b = 0; b < BATCH; ++b) tm += sums[b * 3 + 0];
    out[0] = acc[0] / tm;
}

extern "C" void kernel_launch(void* const* d_in, const int* in_sizes, int n_in,
                              void* d_out, int out_size, void* d_ws, size_t ws_size,
                              hipStream_t stream) {
    const float* pred = (const float*)d_in[0];
    const float* tgt  = (const float*)d_in[1];
    const float* mask = (const float*)d_in[2];
    float* out = (float*)d_out;
    float* ws  = (float*)d_ws;   // [0..47] per-image {Smask,Spred,Stgt}, [48] loss acc

    hipMemsetAsync(d_ws, 0, 49 * sizeof(float), stream);

    dim3 grid(GRIDX, BATCH), blk(BLOCK);
    pass1<<<grid, blk, 0, stream>>>(pred, tgt, mask, ws);
    pass2<<<grid, blk, 0, stream>>>(pred, tgt, mask, ws, ws + 48);
    finalize<<<1, 1, 0, stream>>>(ws, ws + 48, out);
}

// Round 2
// 150.277 us; speedup vs baseline: 2.3911x; 2.3911x over previous
//
#include <hip/hip_runtime.h>

// Geometry fixed by setup_inputs: [16, 1, 352, 1216] fp32.
#define BATCH 16
#define HH    352
#define WW    1216
#define IMG   (HH * WW)
#define QPR   (WW / 4)      // 304 quads (float4 groups) per row
#define ROWS  8             // rows per strip
#define STRIPS (HH / ROWS)  // 44
#define BLOCK 320           // 5 waves; covers one full row (304 quads + 16 idle)
#define NWAVE (BLOCK / 64)

__device__ __forceinline__ float med3f(float a, float b, float c) {
#if defined(__has_builtin) && __has_builtin(__builtin_amdgcn_fmed3f)
    return __builtin_amdgcn_fmed3f(a, b, c);
#else
    return fmaxf(fminf(fmaxf(a, b), c), fminf(a, b));
#endif
}

// Load cols [c0-1 .. c0+4] of row h into o[6], zero-padded at image edges.
// Addresses are clamped so even out-of-range threads load safely.
__device__ __forceinline__ void load_row6(const float* __restrict__ img, int h,
                                          int c0, float o[6]) {
    const bool hv = ((unsigned)h < (unsigned)HH);
    const int hc = hv ? h : 0;
    const float* r = img + hc * WW;
    const int cc = min(c0, WW - 4);
    float4 v = *reinterpret_cast<const float4*>(r + cc);
    float l  = r[max(c0 - 1, 0)];
    float rt = r[min(c0 + 4, WW - 1)];
    o[1] = hv ? v.x : 0.f;
    o[2] = hv ? v.y : 0.f;
    o[3] = hv ? v.z : 0.f;
    o[4] = hv ? v.w : 0.f;
    o[0] = (hv && c0 > 0)      ? l  : 0.f;
    o[5] = (hv && c0 + 4 < WW) ? rt : 0.f;
}

// contrast[i] = center - exact median3x3, for 4 pixels, from 3 row segments.
// Column sort3 (6 ops/col) + med3(max3(lo), med3(mid), min3(hi)) per pixel.
__device__ __forceinline__ void contrast4(const float rp[6], const float rc[6],
                                          const float rn[6], float c[4]) {
    float lo[6], mid[6], hi[6];
#pragma unroll
    for (int j = 0; j < 6; ++j) {
        float a = rp[j], b = rc[j], d = rn[j];
        float t0 = fminf(a, b), t1 = fmaxf(a, b);
        float t2 = fminf(t1, d);
        hi[j]  = fmaxf(t1, d);
        lo[j]  = fminf(t0, t2);
        mid[j] = fmaxf(t0, t2);
    }
#pragma unroll
    for (int i = 0; i < 4; ++i) {
        float mx = fmaxf(fmaxf(lo[i], lo[i + 1]), lo[i + 2]);
        float md = med3f(mid[i], mid[i + 1], mid[i + 2]);
        float mn = fminf(fminf(hi[i], hi[i + 1]), hi[i + 2]);
        c[i] = rc[i + 1] - med3f(mx, md, mn);
    }
}

__device__ __forceinline__ float waveRed(float v) {
#pragma unroll
    for (int o = 32; o > 0; o >>= 1) v += __shfl_down(v, o, 64);
    return v;
}

// Pass 1: per-image sums of {mask, mask*|pred_contrast|, mask*|target_contrast|}.
__global__ __launch_bounds__(BLOCK) void pass1(const float* __restrict__ pred,
                                               const float* __restrict__ tgt,
                                               const float* __restrict__ mask,
                                               float* __restrict__ sums) {
    const int b  = blockIdx.y;
    const int r0 = blockIdx.x * ROWS;
    const int q  = threadIdx.x;
    const int c0 = q * 4;
    const bool qv = q < QPR;

    const float* pimg = pred + b * IMG;
    const float* timg = tgt  + b * IMG;
    const float* mimg = mask + b * IMG;

    float P[3][6], T[3][6];
    load_row6(pimg, r0 - 1, c0, P[0]);
    load_row6(pimg, r0,     c0, P[1]);
    load_row6(timg, r0 - 1, c0, T[0]);
    load_row6(timg, r0,     c0, T[1]);

    float s_m = 0.f, s_p = 0.f, s_t = 0.f;
#pragma unroll
    for (int i = 0; i < ROWS; ++i) {
        const int h = r0 + i;
        load_row6(pimg, h + 1, c0, P[(i + 2) % 3]);
        load_row6(timg, h + 1, c0, T[(i + 2) % 3]);
        float4 m4 = *reinterpret_cast<const float4*>(mimg + h * WW + min(c0, WW - 4));

        float pc[4], tc[4];
        contrast4(P[i % 3], P[(i + 1) % 3], P[(i + 2) % 3], pc);
        contrast4(T[i % 3], T[(i + 1) % 3], T[(i + 2) % 3], tc);

        float mv[4] = {m4.x, m4.y, m4.z, m4.w};
#pragma unroll
        for (int k = 0; k < 4; ++k) {
            s_m += mv[k];
            s_p += mv[k] * fabsf(pc[k]);
            s_t += mv[k] * fabsf(tc[k]);
        }
    }
    if (!qv) { s_m = 0.f; s_p = 0.f; s_t = 0.f; }

    s_m = waveRed(s_m); s_p = waveRed(s_p); s_t = waveRed(s_t);

    __shared__ float red[3][NWAVE];
    const int lane = threadIdx.x & 63, wid = threadIdx.x >> 6;
    if (lane == 0) { red[0][wid] = s_m; red[1][wid] = s_p; red[2][wid] = s_t; }
    __syncthreads();
    if (threadIdx.x == 0) {
        float a0 = 0.f, a1 = 0.f, a2 = 0.f;
#pragma unroll
        for (int w = 0; w < NWAVE; ++w) { a0 += red[0][w]; a1 += red[1][w]; a2 += red[2][w]; }
        atomicAdd(&sums[b * 3 + 0], a0);
        atomicAdd(&sums[b * 3 + 1], a1);
        atomicAdd(&sums[b * 3 + 2], a2);
    }
}

// Pass 2: per-image sum of |pc/mean_pred - tc/mean_target|.
__global__ __launch_bounds__(BLOCK) void pass2(const float* __restrict__ pred,
                                               const float* __restrict__ tgt,
                                               const float* __restrict__ sums,
                                               float* __restrict__ acc) {
    const int b = blockIdx.y;
    const float denom  = sums[b * 3 + 0];
    const float inv_mp = denom / sums[b * 3 + 1];
    const float inv_mt = denom / sums[b * 3 + 2];

    const int r0 = blockIdx.x * ROWS;
    const int q  = threadIdx.x;
    const int c0 = q * 4;
    const bool qv = q < QPR;

    const float* pimg = pred + b * IMG;
    const float* timg = tgt  + b * IMG;

    float P[3][6], T[3][6];
    load_row6(pimg, r0 - 1, c0, P[0]);
    load_row6(pimg, r0,     c0, P[1]);
    load_row6(timg, r0 - 1, c0, T[0]);
    load_row6(timg, r0,     c0, T[1]);

    float s = 0.f;
#pragma unroll
    for (int i = 0; i < ROWS; ++i) {
        const int h = r0 + i;
        load_row6(pimg, h + 1, c0, P[(i + 2) % 3]);
        load_row6(timg, h + 1, c0, T[(i + 2) % 3]);

        float pc[4], tc[4];
        contrast4(P[i % 3], P[(i + 1) % 3], P[(i + 2) % 3], pc);
        contrast4(T[i % 3], T[(i + 1) % 3], T[(i + 2) % 3], tc);

#pragma unroll
        for (int k = 0; k < 4; ++k)
            s += fabsf(pc[k] * inv_mp - tc[k] * inv_mt);
    }
    if (!qv) s = 0.f;

    s = waveRed(s);

    __shared__ float red[NWAVE];
    const int lane = threadIdx.x & 63, wid = threadIdx.x >> 6;
    if (lane == 0) red[wid] = s;
    __syncthreads();
    if (threadIdx.x == 0) {
        float a = 0.f;
#pragma unroll
        for (int w = 0; w < NWAVE; ++w) a += red[w];
        atomicAdd(&acc[b], a);
    }
}

__global__ void finalize(const float* __restrict__ sums,
                         const float* __restrict__ acc,
                         float* __restrict__ out) {
    float tm = 0.f, ta = 0.f;
    for (int b = 0; b < BATCH; ++b) { tm += sums[b * 3 + 0]; ta += acc[b]; }
    out[0] = ta / tm;
}

extern "C" void kernel_launch(void* const* d_in, const int* in_sizes, int n_in,
                              void* d_out, int out_size, void* d_ws, size_t ws_size,
                              hipStream_t stream) {
    const float* pred = (const float*)d_in[0];
    const float* tgt  = (const float*)d_in[1];
    const float* mask = (const float*)d_in[2];
    float* out = (float*)d_out;
    float* ws  = (float*)d_ws;  // [0..47] per-image {Sm,Sp,St}; [48..63] per-image loss acc

    hipMemsetAsync(d_ws, 0, 64 * sizeof(float), stream);

    dim3 grid(STRIPS, BATCH), blk(BLOCK);
    pass1<<<grid, blk, 0, stream>>>(pred, tgt, mask, ws);
    pass2<<<grid, blk, 0, stream>>>(pred, tgt, ws, ws + 48);
    finalize<<<1, 1, 0, stream>>>(ws, ws + 48, out);
}